// Round 3
// baseline (5279.554 us; speedup 1.0000x reference)
//
#include <hip/hip_runtime.h>
#include <math.h>

namespace {

constexpr int T_STEPS = 512;
constexpr int NGRP    = 64;   // row-groups of 16 rows
constexpr int D_RING  = 8;    // ring slots per group (4 KB each)

typedef _Float16 h8v __attribute__((ext_vector_type(8)));
typedef _Float16 h2v __attribute__((ext_vector_type(2)));
typedef float    f4v __attribute__((ext_vector_type(4)));

__device__ __forceinline__ float sigf(float v) { return 1.0f / (1.0f + __expf(-v)); }
__device__ __forceinline__ float tanh_(float v) { return 2.0f / (1.0f + __expf(-2.0f * v)) - 1.0f; }

// Pack weights into MFMA B-fragment load order, fp16.
// PA (layer0): frag f = (w*4+q)*6 + ks, elem [l][j]:
//   gate = 16*(8q+w) + (l&15), k = 32*ks + 8*(l>>4) + j ; ks 0-1 from Wih0 (K=64),
//   ks 2-5 from Whh0 (K=128). PB (layer1): 8 ks: 0-3 Wih1, 4-7 Whh1.
__global__ void pack_w(const float* __restrict__ Wih0, const float* __restrict__ Whh0,
                       const float* __restrict__ Wih1, const float* __restrict__ Whh1,
                       _Float16* __restrict__ PA, _Float16* __restrict__ PB) {
  int idx = blockIdx.x * 256 + threadIdx.x;
  if (idx < 98304) {
    int j = idx & 7, l = (idx >> 3) & 63;
    int f = idx >> 9;
    int ks = f % 6, wq = f / 6;
    int q = wq & 3, w = wq >> 2;
    int gate = 16 * (8 * q + w) + (l & 15);
    int k = 32 * ks + ((l >> 4) << 3) + j;
    float v = (k < 64) ? Wih0[gate * 64 + k] : Whh0[gate * 128 + (k - 64)];
    PA[idx] = (_Float16)v;
  } else if (idx < 98304 + 131072) {
    int i = idx - 98304;
    int j = i & 7, l = (i >> 3) & 63;
    int f = i >> 9;
    int ks = f & 7, wq = f >> 3;
    int q = wq & 3, w = wq >> 2;
    int gate = 16 * (8 * q + w) + (l & 15);
    int k = 32 * ks + ((l >> 4) << 3) + j;
    float v = (k < 128) ? Wih1[gate * 128 + k] : Whh1[gate * 128 + (k - 128)];
    PB[i] = (_Float16)v;
  }
}

// 128 blocks x 512 threads. Blocks 0..63: layer-0 producers (group g = blockIdx).
// Blocks 64..127: layer-1 consumers (group g = blockIdx-64). Group g owns batch
// rows [16g, 16g+16). Weights live in registers (B-fragments, loaded once).
// h0(t) flows producer->consumer through an L2-resident ring (tiled A-frag
// layout, 4 KB/slot). In-wave LSTM state: wave w owns units [16w,16w+16);
// lane holds i,f,g,o accs for its (row,unit); c in registers.
__global__ __launch_bounds__(512, 2) void lstm_pipe(
    const float* __restrict__ x,
    const _Float16* __restrict__ PA, const _Float16* __restrict__ PB,
    const float* __restrict__ b0, const float* __restrict__ b1,
    const float* __restrict__ Wout, const float* __restrict__ bout,
    _Float16* __restrict__ ring, int* __restrict__ flagv, int* __restrict__ progv,
    float* __restrict__ out) {
  const int tid = threadIdx.x;
  const int w = tid >> 6;          // wave 0..7
  const int l = tid & 63;
  const int lo = l & 15, hi = l >> 4;
  const bool isA = (blockIdx.x < NGRP);
  const int g = isA ? blockIdx.x : (blockIdx.x - NGRP);

  // Tiled f16 activation tiles: [kb][lane][8]; A-frag read = ds_read_b128 at lane*16.
  __shared__ _Float16 h0t[4][64][8];      // producer: own h0 | consumer: staged slot
  __shared__ _Float16 h1t[4][64][8];      // consumer h1
  __shared__ _Float16 xt[2][2][64][8];    // producer x double-buffer

  unsigned long long* ring64 = (unsigned long long*)ring;

  const int unit = 16 * w + lo;
  const int kb_w = w >> 1;
  const int sub_w = (2 * w + (lo >> 3)) & 3;
  const int lanep = sub_w * 16 + hi * 4;  // + r
  const int jw = lo & 7;

  if (isA) {
    // ---------------- layer-0 producer ----------------
    const float bi = b0[unit], bf = b0[unit + 128], bg = b0[unit + 256], bo = b0[unit + 384];
    h8v WB[4][6];
#pragma unroll
    for (int q = 0; q < 4; ++q)
#pragma unroll
      for (int ks = 0; ks < 6; ++ks)
        WB[q][ks] = ((const h8v*)PA)[((w * 4 + q) * 6 + ks) * 64 + l];
    float c0[4] = {0.f, 0.f, 0.f, 0.f};
    ((unsigned long long*)h0t)[tid] = 0ull;  // h0(-1) = 0
    {
      int row = tid >> 5, kk = (tid & 31) << 1;
      const float* xp = x + (((long)(g * 16 + row)) * T_STEPS + 0) * 64 + kk;
      float2 v = *(const float2*)xp;
      h2v p; p.x = (_Float16)v.x; p.y = (_Float16)v.y;
      *(h2v*)&xt[0][kk >> 5][(((kk >> 3) & 3) * 16) + row][kk & 7] = p;
    }
    __syncthreads();

    for (int t = 0; t < T_STEPS; ++t) {
      const int buf = t & 1;
      h8v a0 = *(const h8v*)&xt[buf][0][l][0];
      h8v a1 = *(const h8v*)&xt[buf][1][l][0];
      h8v a2 = *(const h8v*)&h0t[0][l][0];
      h8v a3 = *(const h8v*)&h0t[1][l][0];
      h8v a4 = *(const h8v*)&h0t[2][l][0];
      h8v a5 = *(const h8v*)&h0t[3][l][0];
      f4v acc[4];
#pragma unroll
      for (int q = 0; q < 4; ++q) {
        f4v z = {0.f, 0.f, 0.f, 0.f};
        z = __builtin_amdgcn_mfma_f32_16x16x32_f16(a0, WB[q][0], z, 0, 0, 0);
        z = __builtin_amdgcn_mfma_f32_16x16x32_f16(a1, WB[q][1], z, 0, 0, 0);
        z = __builtin_amdgcn_mfma_f32_16x16x32_f16(a2, WB[q][2], z, 0, 0, 0);
        z = __builtin_amdgcn_mfma_f32_16x16x32_f16(a3, WB[q][3], z, 0, 0, 0);
        z = __builtin_amdgcn_mfma_f32_16x16x32_f16(a4, WB[q][4], z, 0, 0, 0);
        z = __builtin_amdgcn_mfma_f32_16x16x32_f16(a5, WB[q][5], z, 0, 0, 0);
        acc[q] = z;
      }
      float hv[4];
#pragma unroll
      for (int r = 0; r < 4; ++r) {
        float zi = acc[0][r] + bi, zf = acc[1][r] + bf;
        float zg = acc[2][r] + bg, zo = acc[3][r] + bo;
        float cn = sigf(zf) * c0[r] + sigf(zi) * tanh_(zg);
        c0[r] = cn;
        hv[r] = sigf(zo) * tanh_(cn);
      }
      __syncthreads();  // all A-frag reads done
#pragma unroll
      for (int r = 0; r < 4; ++r)
        h0t[kb_w][lanep + r][jw] = (_Float16)hv[r];
      if (t + 1 < T_STEPS) {  // prefetch x(t+1) into other buffer
        int row = tid >> 5, kk = (tid & 31) << 1;
        const float* xp = x + (((long)(g * 16 + row)) * T_STEPS + (t + 1)) * 64 + kk;
        float2 v = *(const float2*)xp;
        h2v p; p.x = (_Float16)v.x; p.y = (_Float16)v.y;
        *(h2v*)&xt[buf ^ 1][kk >> 5][(((kk >> 3) & 3) * 16) + row][kk & 7] = p;
      }
      __syncthreads();  // h0t complete
      if (t >= D_RING) {  // backpressure: slot t%D free once consumer did t-D
        while (__hip_atomic_load(progv + g * 32, __ATOMIC_ACQUIRE,
                                 __HIP_MEMORY_SCOPE_AGENT) < t - D_RING + 1)
          __builtin_amdgcn_s_sleep(2);
      }
      unsigned long long* dst = ring64 + ((long)(g * D_RING + (t & (D_RING - 1)))) * 512;
      dst[tid] = ((const unsigned long long*)h0t)[tid];
      __syncthreads();  // drains stores (vmcnt) before flag
      if (tid == 0)
        __hip_atomic_store(flagv + g * 32, t + 1, __ATOMIC_RELEASE,
                           __HIP_MEMORY_SCOPE_AGENT);
    }
  } else {
    // ---------------- layer-1 consumer ----------------
    const float bi = b1[unit], bf = b1[unit + 128], bg = b1[unit + 256], bo = b1[unit + 384];
    h8v WB[4][8];
#pragma unroll
    for (int q = 0; q < 4; ++q)
#pragma unroll
      for (int ks = 0; ks < 8; ++ks)
        WB[q][ks] = ((const h8v*)PB)[((w * 4 + q) * 8 + ks) * 64 + l];
    float c1[4] = {0.f, 0.f, 0.f, 0.f};
    ((unsigned long long*)h1t)[tid] = 0ull;  // h1(-1) = 0
    __syncthreads();

    for (int t = 0; t < T_STEPS; ++t) {
      while (__hip_atomic_load(flagv + g * 32, __ATOMIC_ACQUIRE,
                               __HIP_MEMORY_SCOPE_AGENT) < t + 1)
        __builtin_amdgcn_s_sleep(2);
      const unsigned long long* src =
          ring64 + ((long)(g * D_RING + (t & (D_RING - 1)))) * 512;
      ((unsigned long long*)h0t)[tid] = src[tid];
      __syncthreads();  // copy-in complete
      if (tid == 0)
        __hip_atomic_store(progv + g * 32, t + 1, __ATOMIC_RELEASE,
                           __HIP_MEMORY_SCOPE_AGENT);
      h8v a0 = *(const h8v*)&h0t[0][l][0];
      h8v a1 = *(const h8v*)&h0t[1][l][0];
      h8v a2 = *(const h8v*)&h0t[2][l][0];
      h8v a3 = *(const h8v*)&h0t[3][l][0];
      h8v a4 = *(const h8v*)&h1t[0][l][0];
      h8v a5 = *(const h8v*)&h1t[1][l][0];
      h8v a6 = *(const h8v*)&h1t[2][l][0];
      h8v a7 = *(const h8v*)&h1t[3][l][0];
      f4v acc[4];
#pragma unroll
      for (int q = 0; q < 4; ++q) {
        f4v z = {0.f, 0.f, 0.f, 0.f};
        z = __builtin_amdgcn_mfma_f32_16x16x32_f16(a0, WB[q][0], z, 0, 0, 0);
        z = __builtin_amdgcn_mfma_f32_16x16x32_f16(a1, WB[q][1], z, 0, 0, 0);
        z = __builtin_amdgcn_mfma_f32_16x16x32_f16(a2, WB[q][2], z, 0, 0, 0);
        z = __builtin_amdgcn_mfma_f32_16x16x32_f16(a3, WB[q][3], z, 0, 0, 0);
        z = __builtin_amdgcn_mfma_f32_16x16x32_f16(a4, WB[q][4], z, 0, 0, 0);
        z = __builtin_amdgcn_mfma_f32_16x16x32_f16(a5, WB[q][5], z, 0, 0, 0);
        z = __builtin_amdgcn_mfma_f32_16x16x32_f16(a6, WB[q][6], z, 0, 0, 0);
        z = __builtin_amdgcn_mfma_f32_16x16x32_f16(a7, WB[q][7], z, 0, 0, 0);
        acc[q] = z;
      }
      float hv[4];
#pragma unroll
      for (int r = 0; r < 4; ++r) {
        float zi = acc[0][r] + bi, zf = acc[1][r] + bf;
        float zg = acc[2][r] + bg, zo = acc[3][r] + bo;
        float cn = sigf(zf) * c1[r] + sigf(zi) * tanh_(zg);
        c1[r] = cn;
        hv[r] = sigf(zo) * tanh_(cn);
      }
      __syncthreads();  // all h1t reads done
#pragma unroll
      for (int r = 0; r < 4; ++r)
        h1t[kb_w][lanep + r][jw] = (_Float16)hv[r];
      // next iter's post-copy barrier orders these writes before reads
    }
    __syncthreads();
    if (tid < 16) {  // y = h1 . Wout^T + bout
      float acc = bout[0];
#pragma unroll 4
      for (int u = 0; u < 128; ++u) {
        float hval = (float)h1t[u >> 5][(((u >> 3) & 3) * 16) + tid][u & 7];
        acc = fmaf(hval, Wout[u], acc);
      }
      out[g * 16 + tid] = acc;
    }
  }
}

}  // namespace

extern "C" void kernel_launch(void* const* d_in, const int* in_sizes, int n_in,
                              void* d_out, int out_size, void* d_ws, size_t ws_size,
                              hipStream_t stream) {
  const float* x    = (const float*)d_in[0];
  const float* Wih0 = (const float*)d_in[1];
  const float* Whh0 = (const float*)d_in[2];
  const float* b0   = (const float*)d_in[3];
  const float* Wih1 = (const float*)d_in[4];
  const float* Whh1 = (const float*)d_in[5];
  const float* b1   = (const float*)d_in[6];
  const float* Wout = (const float*)d_in[7];
  const float* bout = (const float*)d_in[8];
  float* out = (float*)d_out;

  char* ws = (char*)d_ws;
  _Float16* PA   = (_Float16*)ws;              // 196608 B
  _Float16* PB   = (_Float16*)(ws + 196608);   // 262144 B -> 458752
  _Float16* ring = (_Float16*)(ws + 462848);   // 64*8*4096 = 2 MiB -> 2560000
  int* flagv     = (int*)(ws + 2560000);       // 8 KiB (64 x 128B-padded)
  int* progv     = (int*)(ws + 2568192);       // 8 KiB

  hipMemsetAsync(ws + 2560000, 0, 16384, stream);
  pack_w<<<dim3(896), dim3(256), 0, stream>>>(Wih0, Whh0, Wih1, Whh1, PA, PB);
  lstm_pipe<<<dim3(128), dim3(512), 0, stream>>>(
      x, PA, PB, b0, b1, Wout, bout, ring, flagv, progv, out);
}

// Round 4
// 1888.825 us; speedup vs baseline: 2.7952x; 2.7952x over previous
//
#include <hip/hip_runtime.h>
#include <math.h>

namespace {

constexpr int T_STEPS = 512;

typedef _Float16 h8v __attribute__((ext_vector_type(8)));
typedef _Float16 h2v __attribute__((ext_vector_type(2)));
typedef float    f4v __attribute__((ext_vector_type(4)));

__device__ __forceinline__ float sigf(float v) { return 1.0f / (1.0f + __expf(-v)); }
__device__ __forceinline__ float tanh_(float v) { return 2.0f / (1.0f + __expf(-2.0f * v)) - 1.0f; }

// Pack weights into MFMA B-fragment load order, fp16 (verified on HW in R3).
// PA (layer0): frag f = (w*4+q)*6 + ks, elem [l][j]:
//   gate = 16*(8q+w) + (l&15), k = 32*ks + 8*(l>>4) + j ; ks 0-1 Wih0, ks 2-5 Whh0.
// PB (layer1): 8 ks: 0-3 Wih1, 4-7 Whh1.
__global__ void pack_w(const float* __restrict__ Wih0, const float* __restrict__ Whh0,
                       const float* __restrict__ Wih1, const float* __restrict__ Whh1,
                       _Float16* __restrict__ PA, _Float16* __restrict__ PB) {
  int idx = blockIdx.x * 256 + threadIdx.x;
  if (idx < 98304) {
    int j = idx & 7, l = (idx >> 3) & 63;
    int f = idx >> 9;
    int ks = f % 6, wq = f / 6;
    int q = wq & 3, w = wq >> 2;
    int gate = 16 * (8 * q + w) + (l & 15);
    int k = 32 * ks + ((l >> 4) << 3) + j;
    float v = (k < 64) ? Wih0[gate * 64 + k] : Whh0[gate * 128 + (k - 64)];
    PA[idx] = (_Float16)v;
  } else if (idx < 98304 + 131072) {
    int i = idx - 98304;
    int j = i & 7, l = (i >> 3) & 63;
    int f = i >> 9;
    int ks = f & 7, wq = f >> 3;
    int q = wq & 3, w = wq >> 2;
    int gate = 16 * (8 * q + w) + (l & 15);
    int k = 32 * ks + ((l >> 4) << 3) + j;
    float v = (k < 128) ? Wih1[gate * 128 + k] : Whh1[gate * 128 + (k - 128)];
    PB[i] = (_Float16)v;
  }
}

// 64 blocks x 512 threads (8 waves), 1 block/CU. Block owns 16 batch rows and
// computes BOTH layers each step (phase A = layer0, phase B = layer1), handing
// h0 across via LDS — zero inter-block traffic. Weights: W0 (96 KB) + Wih1
// (64 KB) register-resident B-fragments; Whh1 (128 KB) pre-staged B-fragments
// in LDS. In-wave LSTM state: wave w owns units [16w,16w+16); lane holds all
// 4 gate accs for its (row,unit); c in registers (fp32, never quantized).
__global__ __launch_bounds__(512, 2) void lstm_block(
    const float* __restrict__ x,
    const _Float16* __restrict__ PA, const _Float16* __restrict__ PB,
    const float* __restrict__ b0, const float* __restrict__ b1,
    const float* __restrict__ Wout, const float* __restrict__ bout,
    float* __restrict__ out) {
  extern __shared__ char smem[];
  h8v* whh = (h8v*)smem;  // Whh1 B-frags: [32 wq][4 ks4][64 l] = 128 KB
  _Float16(*h0t)[4][64][8] = (_Float16(*)[4][64][8])(smem + 131072);          // [2][4][64][8] 8 KB
  _Float16(*h1t)[4][64][8] = (_Float16(*)[4][64][8])(smem + 131072 + 8192);   // 8 KB
  _Float16(*xt)[2][64][8]  = (_Float16(*)[2][64][8])(smem + 131072 + 16384);  // [2][2][64][8] 4 KB

  const int tid = threadIdx.x;
  const int g = blockIdx.x;
  const int w = tid >> 6, l = tid & 63;
  const int lo = l & 15, hi = l >> 4;
  const int unit = 16 * w + lo;
  const int kb_w = w >> 1;
  const int sub_w = (2 * w + (lo >> 3)) & 3;
  const int lanep = sub_w * 16 + hi * 4;  // + r
  const int jw = lo & 7;

  // ---- persistent register weights ----
  const h8v* PAv = (const h8v*)PA;
  const h8v* PBv = (const h8v*)PB;
  h8v W0[4][6], W1[4][4];
#pragma unroll
  for (int q = 0; q < 4; ++q) {
#pragma unroll
    for (int ks = 0; ks < 6; ++ks) W0[q][ks] = PAv[((w * 4 + q) * 6 + ks) * 64 + l];
#pragma unroll
    for (int ks = 0; ks < 4; ++ks) W1[q][ks] = PBv[((w * 4 + q) * 8 + ks) * 64 + l];
  }
  float bA[4], bB[4];
#pragma unroll
  for (int q = 0; q < 4; ++q) { bA[q] = b0[unit + 128 * q]; bB[q] = b1[unit + 128 * q]; }
  float c0[4] = {0.f, 0.f, 0.f, 0.f}, c1[4] = {0.f, 0.f, 0.f, 0.f};

  // ---- stage Whh1 fragments into LDS ----
  for (int i = tid; i < 8192; i += 512) {
    int l2 = i & 63, f = i >> 6;
    int ks4 = f & 3, wq = f >> 2;
    whh[i] = PBv[(wq * 8 + 4 + ks4) * 64 + l2];
  }
  // ---- zero h0t/h1t, stage x(0) ----
  {
    unsigned int* z0 = (unsigned int*)h0t;
    unsigned int* z1 = (unsigned int*)h1t;
    for (int i = tid; i < 2048; i += 512) { z0[i] = 0u; z1[i] = 0u; }
    int row = tid >> 5, kk = (tid & 31) << 1;
    const float* xp = x + (((long)(g * 16 + row)) * T_STEPS + 0) * 64 + kk;
    float2 v = *(const float2*)xp;
    h2v pxv; pxv.x = (_Float16)v.x; pxv.y = (_Float16)v.y;
    *(h2v*)&xt[0][kk >> 5][(((kk >> 3) & 3) * 16) + row][kk & 7] = pxv;
  }
  __syncthreads();

  for (int t = 0; t < T_STEPS; ++t) {
    const int p = t & 1;

    // ---------- phase A : layer 0 computes h0(t) ----------
    {
      h8v ax0 = *(const h8v*)&xt[p][0][l][0];
      h8v ax1 = *(const h8v*)&xt[p][1][l][0];
      h8v ah0 = *(const h8v*)&h0t[p][0][l][0];
      h8v ah1 = *(const h8v*)&h0t[p][1][l][0];
      h8v ah2 = *(const h8v*)&h0t[p][2][l][0];
      h8v ah3 = *(const h8v*)&h0t[p][3][l][0];
      f4v acc[4];
#pragma unroll
      for (int q = 0; q < 4; ++q) {
        f4v z = {bA[q], bA[q], bA[q], bA[q]};
        z = __builtin_amdgcn_mfma_f32_16x16x32_f16(ax0, W0[q][0], z, 0, 0, 0);
        z = __builtin_amdgcn_mfma_f32_16x16x32_f16(ax1, W0[q][1], z, 0, 0, 0);
        z = __builtin_amdgcn_mfma_f32_16x16x32_f16(ah0, W0[q][2], z, 0, 0, 0);
        z = __builtin_amdgcn_mfma_f32_16x16x32_f16(ah1, W0[q][3], z, 0, 0, 0);
        z = __builtin_amdgcn_mfma_f32_16x16x32_f16(ah2, W0[q][4], z, 0, 0, 0);
        z = __builtin_amdgcn_mfma_f32_16x16x32_f16(ah3, W0[q][5], z, 0, 0, 0);
        acc[q] = z;
      }
#pragma unroll
      for (int r = 0; r < 4; ++r) {
        float cn = sigf(acc[1][r]) * c0[r] + sigf(acc[0][r]) * tanh_(acc[2][r]);
        c0[r] = cn;
        float hv = sigf(acc[3][r]) * tanh_(cn);
        h0t[p ^ 1][kb_w][lanep + r][jw] = (_Float16)hv;
      }
    }
    __syncthreads();  // h0(t) visible to all waves

    // ---------- phase B : layer 1 computes h1(t) ----------
    {
      h8v f00 = *(const h8v*)&h0t[p ^ 1][0][l][0];
      h8v f01 = *(const h8v*)&h0t[p ^ 1][1][l][0];
      h8v f02 = *(const h8v*)&h0t[p ^ 1][2][l][0];
      h8v f03 = *(const h8v*)&h0t[p ^ 1][3][l][0];
      h8v f10 = *(const h8v*)&h1t[p][0][l][0];
      h8v f11 = *(const h8v*)&h1t[p][1][l][0];
      h8v f12 = *(const h8v*)&h1t[p][2][l][0];
      h8v f13 = *(const h8v*)&h1t[p][3][l][0];
      f4v acc[4];
#pragma unroll
      for (int q = 0; q < 4; ++q) {
        const h8v* wb = &whh[((w * 4 + q) * 4) * 64 + l];
        h8v wh0 = wb[0];
        h8v wh1 = wb[64];
        h8v wh2 = wb[128];
        h8v wh3 = wb[192];
        f4v z = {bB[q], bB[q], bB[q], bB[q]};
        z = __builtin_amdgcn_mfma_f32_16x16x32_f16(f00, W1[q][0], z, 0, 0, 0);
        z = __builtin_amdgcn_mfma_f32_16x16x32_f16(f01, W1[q][1], z, 0, 0, 0);
        z = __builtin_amdgcn_mfma_f32_16x16x32_f16(f02, W1[q][2], z, 0, 0, 0);
        z = __builtin_amdgcn_mfma_f32_16x16x32_f16(f03, W1[q][3], z, 0, 0, 0);
        z = __builtin_amdgcn_mfma_f32_16x16x32_f16(f10, wh0, z, 0, 0, 0);
        z = __builtin_amdgcn_mfma_f32_16x16x32_f16(f11, wh1, z, 0, 0, 0);
        z = __builtin_amdgcn_mfma_f32_16x16x32_f16(f12, wh2, z, 0, 0, 0);
        z = __builtin_amdgcn_mfma_f32_16x16x32_f16(f13, wh3, z, 0, 0, 0);
        acc[q] = z;
      }
#pragma unroll
      for (int r = 0; r < 4; ++r) {
        float cn = sigf(acc[1][r]) * c1[r] + sigf(acc[0][r]) * tanh_(acc[2][r]);
        c1[r] = cn;
        float hv = sigf(acc[3][r]) * tanh_(cn);
        h1t[p ^ 1][kb_w][lanep + r][jw] = (_Float16)hv;
      }
      if (t + 1 < T_STEPS) {  // prefetch x(t+1)
        int row = tid >> 5, kk = (tid & 31) << 1;
        const float* xp = x + (((long)(g * 16 + row)) * T_STEPS + (t + 1)) * 64 + kk;
        float2 v = *(const float2*)xp;
        h2v pxv; pxv.x = (_Float16)v.x; pxv.y = (_Float16)v.y;
        *(h2v*)&xt[p ^ 1][kk >> 5][(((kk >> 3) & 3) * 16) + row][kk & 7] = pxv;
      }
    }
    __syncthreads();  // h1(t), x(t+1) visible for next step
  }

  // ---- output projection: y = h1(T-1) . Wout^T + bout ; h1(T-1) in h1t[0] ----
  if (tid < 16) {
    float acc = bout[0];
#pragma unroll 4
    for (int u = 0; u < 128; ++u) {
      float hval = (float)h1t[0][u >> 5][(((u >> 3) & 3) * 16) + tid][u & 7];
      acc = fmaf(hval, Wout[u], acc);
    }
    out[g * 16 + tid] = acc;
  }
}

}  // namespace

extern "C" void kernel_launch(void* const* d_in, const int* in_sizes, int n_in,
                              void* d_out, int out_size, void* d_ws, size_t ws_size,
                              hipStream_t stream) {
  const float* x    = (const float*)d_in[0];
  const float* Wih0 = (const float*)d_in[1];
  const float* Whh0 = (const float*)d_in[2];
  const float* b0   = (const float*)d_in[3];
  const float* Wih1 = (const float*)d_in[4];
  const float* Whh1 = (const float*)d_in[5];
  const float* b1   = (const float*)d_in[6];
  const float* Wout = (const float*)d_in[7];
  const float* bout = (const float*)d_in[8];
  float* out = (float*)d_out;

  char* ws = (char*)d_ws;
  _Float16* PA = (_Float16*)ws;             // 196608 B
  _Float16* PB = (_Float16*)(ws + 196608);  // 262144 B

  const int lds_bytes = 131072 + 8192 + 8192 + 4096;  // 151552
  hipFuncSetAttribute((const void*)lstm_block,
                      hipFuncAttributeMaxDynamicSharedMemorySize, lds_bytes);

  pack_w<<<dim3(896), dim3(256), 0, stream>>>(Wih0, Whh0, Wih1, Whh1, PA, PB);
  lstm_block<<<dim3(64), dim3(512), lds_bytes, stream>>>(
      x, PA, PB, b0, b1, Wout, bout, out);
}

// Round 5
// 1878.112 us; speedup vs baseline: 2.8111x; 1.0057x over previous
//
#include <hip/hip_runtime.h>
#include <math.h>

namespace {

constexpr int T_STEPS = 512;

typedef _Float16 h8v __attribute__((ext_vector_type(8)));
typedef _Float16 h2v __attribute__((ext_vector_type(2)));
typedef float    f4v __attribute__((ext_vector_type(4)));

__device__ __forceinline__ float sigf(float v) { return 1.0f / (1.0f + __expf(-v)); }
__device__ __forceinline__ float tanh_(float v) { return 2.0f / (1.0f + __expf(-2.0f * v)) - 1.0f; }

// Pack weights into MFMA B-fragment load order, fp16 (verified on HW R3/R4).
// PA (layer0): frag f = (w*4+q)*6 + ks, elem [l][j]:
//   gate = 16*(8q+w) + (l&15), k = 32*ks + 8*(l>>4) + j ; ks 0-1 Wih0, ks 2-5 Whh0.
// PB (layer1): 8 ks: 0-3 Wih1, 4-7 Whh1.
__global__ void pack_w(const float* __restrict__ Wih0, const float* __restrict__ Whh0,
                       const float* __restrict__ Wih1, const float* __restrict__ Whh1,
                       _Float16* __restrict__ PA, _Float16* __restrict__ PB) {
  int idx = blockIdx.x * 256 + threadIdx.x;
  if (idx < 98304) {
    int j = idx & 7, l = (idx >> 3) & 63;
    int f = idx >> 9;
    int ks = f % 6, wq = f / 6;
    int q = wq & 3, w = wq >> 2;
    int gate = 16 * (8 * q + w) + (l & 15);
    int k = 32 * ks + ((l >> 4) << 3) + j;
    float v = (k < 64) ? Wih0[gate * 64 + k] : Whh0[gate * 128 + (k - 64)];
    PA[idx] = (_Float16)v;
  } else if (idx < 98304 + 131072) {
    int i = idx - 98304;
    int j = i & 7, l = (i >> 3) & 63;
    int f = i >> 9;
    int ks = f & 7, wq = f >> 3;
    int q = wq & 3, w = wq >> 2;
    int gate = 16 * (8 * q + w) + (l & 15);
    int k = 32 * ks + ((l >> 4) << 3) + j;
    float v = (k < 128) ? Wih1[gate * 128 + k] : Whh1[gate * 128 + (k - 128)];
    PB[i] = (_Float16)v;
  }
}

// 64 blocks x 512 threads (8 waves), 1 block/CU. Block owns 16 batch rows and
// computes BOTH layers each step (phase A = layer0, phase B = layer1), handing
// h0 across via LDS — zero inter-block traffic. Weights: W0 (96 KB) + Wih1
// (64 KB) PINNED register-resident B-fragments (asm anchor prevents the
// compiler rematerializing the global loads inside the t-loop — R4's bug:
// VGPR_Count=128 < the 160 needed, i.e. weights were re-streamed from L2
// every step); Whh1 (128 KB) pre-staged B-fragments in LDS. In-wave LSTM
// state: wave w owns units [16w,16w+16); lane holds all 4 gate accs for its
// (row,unit); c in registers (fp32, never quantized).
__global__ __launch_bounds__(512, 2) void lstm_block(
    const float* __restrict__ x,
    const _Float16* __restrict__ PA, const _Float16* __restrict__ PB,
    const float* __restrict__ b0, const float* __restrict__ b1,
    const float* __restrict__ Wout, const float* __restrict__ bout,
    float* __restrict__ out) {
  extern __shared__ char smem[];
  h8v* whh = (h8v*)smem;  // Whh1 B-frags: [32 wq][4 ks4][64 l] = 128 KB
  _Float16(*h0t)[4][64][8] = (_Float16(*)[4][64][8])(smem + 131072);          // [2][4][64][8] 8 KB
  _Float16(*h1t)[4][64][8] = (_Float16(*)[4][64][8])(smem + 131072 + 8192);   // 8 KB
  _Float16(*xt)[2][64][8]  = (_Float16(*)[2][64][8])(smem + 131072 + 16384);  // [2][2][64][8] 4 KB

  const int tid = threadIdx.x;
  const int g = blockIdx.x;
  const int w = tid >> 6, l = tid & 63;
  const int lo = l & 15, hi = l >> 4;
  const int unit = 16 * w + lo;
  const int kb_w = w >> 1;
  const int sub_w = (2 * w + (lo >> 3)) & 3;
  const int lanep = sub_w * 16 + hi * 4;  // + r
  const int jw = lo & 7;

  // ---- persistent register weights (pinned) ----
  const h8v* PAv = (const h8v*)PA;
  const h8v* PBv = (const h8v*)PB;
  h8v W0[4][6], W1[4][4];
#pragma unroll
  for (int q = 0; q < 4; ++q) {
#pragma unroll
    for (int ks = 0; ks < 6; ++ks) W0[q][ks] = PAv[((w * 4 + q) * 6 + ks) * 64 + l];
#pragma unroll
    for (int ks = 0; ks < 4; ++ks) W1[q][ks] = PBv[((w * 4 + q) * 8 + ks) * 64 + l];
  }
  // Anchor: force the fragments to be materialized HERE and stay live across
  // the t-loop; without this the compiler sinks the global loads into the loop.
#pragma unroll
  for (int q = 0; q < 4; ++q) {
#pragma unroll
    for (int ks = 0; ks < 6; ++ks) asm volatile("" : "+v"(W0[q][ks]));
#pragma unroll
    for (int ks = 0; ks < 4; ++ks) asm volatile("" : "+v"(W1[q][ks]));
  }
  float bA[4], bB[4];
#pragma unroll
  for (int q = 0; q < 4; ++q) { bA[q] = b0[unit + 128 * q]; bB[q] = b1[unit + 128 * q]; }
  float c0[4] = {0.f, 0.f, 0.f, 0.f}, c1[4] = {0.f, 0.f, 0.f, 0.f};

  // ---- stage Whh1 fragments into LDS ----
  for (int i = tid; i < 8192; i += 512) {
    int l2 = i & 63, f = i >> 6;
    int ks4 = f & 3, wq = f >> 2;
    whh[i] = PBv[(wq * 8 + 4 + ks4) * 64 + l2];
  }
  // ---- zero h0t/h1t, stage x(0) ----
  {
    unsigned int* z0 = (unsigned int*)h0t;
    unsigned int* z1 = (unsigned int*)h1t;
    for (int i = tid; i < 2048; i += 512) { z0[i] = 0u; z1[i] = 0u; }
    int row = tid >> 5, kk = (tid & 31) << 1;
    const float* xp = x + (((long)(g * 16 + row)) * T_STEPS + 0) * 64 + kk;
    float2 v = *(const float2*)xp;
    h2v pxv; pxv.x = (_Float16)v.x; pxv.y = (_Float16)v.y;
    *(h2v*)&xt[0][kk >> 5][(((kk >> 3) & 3) * 16) + row][kk & 7] = pxv;
  }
  __syncthreads();

  for (int t = 0; t < T_STEPS; ++t) {
    const int p = t & 1;

    // ---------- phase A : layer 0 computes h0(t) ----------
    {
      h8v ax0 = *(const h8v*)&xt[p][0][l][0];
      h8v ax1 = *(const h8v*)&xt[p][1][l][0];
      h8v ah0 = *(const h8v*)&h0t[p][0][l][0];
      h8v ah1 = *(const h8v*)&h0t[p][1][l][0];
      h8v ah2 = *(const h8v*)&h0t[p][2][l][0];
      h8v ah3 = *(const h8v*)&h0t[p][3][l][0];
      f4v acc[4];
#pragma unroll
      for (int q = 0; q < 4; ++q) {
        f4v z = {bA[q], bA[q], bA[q], bA[q]};
        z = __builtin_amdgcn_mfma_f32_16x16x32_f16(ax0, W0[q][0], z, 0, 0, 0);
        z = __builtin_amdgcn_mfma_f32_16x16x32_f16(ax1, W0[q][1], z, 0, 0, 0);
        z = __builtin_amdgcn_mfma_f32_16x16x32_f16(ah0, W0[q][2], z, 0, 0, 0);
        z = __builtin_amdgcn_mfma_f32_16x16x32_f16(ah1, W0[q][3], z, 0, 0, 0);
        z = __builtin_amdgcn_mfma_f32_16x16x32_f16(ah2, W0[q][4], z, 0, 0, 0);
        z = __builtin_amdgcn_mfma_f32_16x16x32_f16(ah3, W0[q][5], z, 0, 0, 0);
        acc[q] = z;
      }
#pragma unroll
      for (int r = 0; r < 4; ++r) {
        float cn = sigf(acc[1][r]) * c0[r] + sigf(acc[0][r]) * tanh_(acc[2][r]);
        c0[r] = cn;
        float hv = sigf(acc[3][r]) * tanh_(cn);
        h0t[p ^ 1][kb_w][lanep + r][jw] = (_Float16)hv;
      }
    }
    __syncthreads();  // h0(t) visible to all waves

    // ---------- phase B : layer 1 computes h1(t) ----------
    {
      h8v f00 = *(const h8v*)&h0t[p ^ 1][0][l][0];
      h8v f01 = *(const h8v*)&h0t[p ^ 1][1][l][0];
      h8v f02 = *(const h8v*)&h0t[p ^ 1][2][l][0];
      h8v f03 = *(const h8v*)&h0t[p ^ 1][3][l][0];
      h8v f10 = *(const h8v*)&h1t[p][0][l][0];
      h8v f11 = *(const h8v*)&h1t[p][1][l][0];
      h8v f12 = *(const h8v*)&h1t[p][2][l][0];
      h8v f13 = *(const h8v*)&h1t[p][3][l][0];
      f4v acc[4];
#pragma unroll
      for (int q = 0; q < 4; ++q) {
        const h8v* wb = &whh[((w * 4 + q) * 4) * 64 + l];
        h8v wh0 = wb[0];
        h8v wh1 = wb[64];
        h8v wh2 = wb[128];
        h8v wh3 = wb[192];
        f4v z = {bB[q], bB[q], bB[q], bB[q]};
        z = __builtin_amdgcn_mfma_f32_16x16x32_f16(f00, W1[q][0], z, 0, 0, 0);
        z = __builtin_amdgcn_mfma_f32_16x16x32_f16(f01, W1[q][1], z, 0, 0, 0);
        z = __builtin_amdgcn_mfma_f32_16x16x32_f16(f02, W1[q][2], z, 0, 0, 0);
        z = __builtin_amdgcn_mfma_f32_16x16x32_f16(f03, W1[q][3], z, 0, 0, 0);
        z = __builtin_amdgcn_mfma_f32_16x16x32_f16(f10, wh0, z, 0, 0, 0);
        z = __builtin_amdgcn_mfma_f32_16x16x32_f16(f11, wh1, z, 0, 0, 0);
        z = __builtin_amdgcn_mfma_f32_16x16x32_f16(f12, wh2, z, 0, 0, 0);
        z = __builtin_amdgcn_mfma_f32_16x16x32_f16(f13, wh3, z, 0, 0, 0);
        acc[q] = z;
      }
#pragma unroll
      for (int r = 0; r < 4; ++r) {
        float cn = sigf(acc[1][r]) * c1[r] + sigf(acc[0][r]) * tanh_(acc[2][r]);
        c1[r] = cn;
        float hv = sigf(acc[3][r]) * tanh_(cn);
        h1t[p ^ 1][kb_w][lanep + r][jw] = (_Float16)hv;
      }
      if (t + 1 < T_STEPS) {  // prefetch x(t+1)
        int row = tid >> 5, kk = (tid & 31) << 1;
        const float* xp = x + (((long)(g * 16 + row)) * T_STEPS + (t + 1)) * 64 + kk;
        float2 v = *(const float2*)xp;
        h2v pxv; pxv.x = (_Float16)v.x; pxv.y = (_Float16)v.y;
        *(h2v*)&xt[p ^ 1][kk >> 5][(((kk >> 3) & 3) * 16) + row][kk & 7] = pxv;
      }
    }
    __syncthreads();  // h1(t), x(t+1) visible for next step
  }

  // ---- output projection: y = h1(T-1) . Wout^T + bout ; h1(T-1) in h1t[0] ----
  if (tid < 16) {
    float acc = bout[0];
#pragma unroll 4
    for (int u = 0; u < 128; ++u) {
      float hval = (float)h1t[0][u >> 5][(((u >> 3) & 3) * 16) + tid][u & 7];
      acc = fmaf(hval, Wout[u], acc);
    }
    out[g * 16 + tid] = acc;
  }
}

}  // namespace

extern "C" void kernel_launch(void* const* d_in, const int* in_sizes, int n_in,
                              void* d_out, int out_size, void* d_ws, size_t ws_size,
                              hipStream_t stream) {
  const float* x    = (const float*)d_in[0];
  const float* Wih0 = (const float*)d_in[1];
  const float* Whh0 = (const float*)d_in[2];
  const float* b0   = (const float*)d_in[3];
  const float* Wih1 = (const float*)d_in[4];
  const float* Whh1 = (const float*)d_in[5];
  const float* b1   = (const float*)d_in[6];
  const float* Wout = (const float*)d_in[7];
  const float* bout = (const float*)d_in[8];
  float* out = (float*)d_out;

  char* ws = (char*)d_ws;
  _Float16* PA = (_Float16*)ws;             // 196608 B
  _Float16* PB = (_Float16*)(ws + 196608);  // 262144 B

  const int lds_bytes = 131072 + 8192 + 8192 + 4096;  // 151552
  hipFuncSetAttribute((const void*)lstm_block,
                      hipFuncAttributeMaxDynamicSharedMemorySize, lds_bytes);

  pack_w<<<dim3(896), dim3(256), 0, stream>>>(Wih0, Whh0, Wih1, Whh1, PA, PB);
  lstm_block<<<dim3(64), dim3(512), lds_bytes, stream>>>(
      x, PA, PB, b0, b1, Wout, bout, out);
}

// Round 6
// 1686.997 us; speedup vs baseline: 3.1296x; 1.1133x over previous
//
#include <hip/hip_runtime.h>
#include <math.h>

namespace {

constexpr int T_STEPS = 512;

typedef _Float16 h8v __attribute__((ext_vector_type(8)));
typedef _Float16 h2v __attribute__((ext_vector_type(2)));
typedef float    f4v __attribute__((ext_vector_type(4)));

__device__ __forceinline__ float sigf(float v) { return 1.0f / (1.0f + __expf(-v)); }
__device__ __forceinline__ float tanh_(float v) { return 2.0f / (1.0f + __expf(-2.0f * v)) - 1.0f; }

// Pack weights into MFMA B-fragment load order, fp16 (verified on HW R3-R5).
// PA (layer0): frag f = (w*4+q)*6 + ks, elem [l][j]:
//   gate = 16*(8q+w) + (l&15), k = 32*ks + 8*(l>>4) + j ; ks 0-1 Wih0, ks 2-5 Whh0.
// PB (layer1): 8 ks: 0-3 Wih1, 4-7 Whh1.
__global__ void pack_w(const float* __restrict__ Wih0, const float* __restrict__ Whh0,
                       const float* __restrict__ Wih1, const float* __restrict__ Whh1,
                       _Float16* __restrict__ PA, _Float16* __restrict__ PB) {
  int idx = blockIdx.x * 256 + threadIdx.x;
  if (idx < 98304) {
    int j = idx & 7, l = (idx >> 3) & 63;
    int f = idx >> 9;
    int ks = f % 6, wq = f / 6;
    int q = wq & 3, w = wq >> 2;
    int gate = 16 * (8 * q + w) + (l & 15);
    int k = 32 * ks + ((l >> 4) << 3) + j;
    float v = (k < 64) ? Wih0[gate * 64 + k] : Whh0[gate * 128 + (k - 64)];
    PA[idx] = (_Float16)v;
  } else if (idx < 98304 + 131072) {
    int i = idx - 98304;
    int j = i & 7, l = (i >> 3) & 63;
    int f = i >> 9;
    int ks = f & 7, wq = f >> 3;
    int q = wq & 3, w = wq >> 2;
    int gate = 16 * (8 * q + w) + (l & 15);
    int k = 32 * ks + ((l >> 4) << 3) + j;
    float v = (k < 128) ? Wih1[gate * 128 + k] : Whh1[gate * 128 + (k - 128)];
    PB[i] = (_Float16)v;
  }
}

// 64 blocks x 512 threads (8 waves), 1 block/CU, waves_per_eu pinned to (2,2)
// so the allocator can spend the full 256-reg/wave budget on resident weights.
// FUSED pipeline: iteration j computes layer0 step j AND layer1 step j-1 in
// ONE phase (they are independent: A(j) needs h0(j-1),x(j); B(j-1) needs
// h0(j-1),h1(j-2)) -> one barrier per step, 8 independent MFMA chains, h0
// fragments read once and shared by both layers. Weights: W0+Wih1 (160 regs)
// register-resident; Whh1 (128 KB) B-frags in LDS. In-wave LSTM state: wave w
// owns units [16w,16w+16); lane holds all 4 gate accs for its (row,unit);
// c in fp32 registers (never quantized).
__global__ __attribute__((amdgpu_waves_per_eu(2, 2))) __launch_bounds__(512)
void lstm_block(
    const float* __restrict__ x,
    const _Float16* __restrict__ PA, const _Float16* __restrict__ PB,
    const float* __restrict__ b0, const float* __restrict__ b1,
    const float* __restrict__ Wout, const float* __restrict__ bout,
    float* __restrict__ out) {
  extern __shared__ char smem[];
  h8v* whh = (h8v*)smem;  // Whh1 B-frags: [32 wq][4 ks4][64 l] = 128 KB
  _Float16(*h0t)[4][64][8] = (_Float16(*)[4][64][8])(smem + 131072);          // [2][4][64][8] 8 KB
  _Float16(*h1t)[4][64][8] = (_Float16(*)[4][64][8])(smem + 131072 + 8192);   // 8 KB
  _Float16(*xt)[2][64][8]  = (_Float16(*)[2][64][8])(smem + 131072 + 16384);  // [2][2][64][8] 4 KB

  const int tid = threadIdx.x;
  const int g = blockIdx.x;
  const int w = tid >> 6, l = tid & 63;
  const int lo = l & 15, hi = l >> 4;
  const int unit = 16 * w + lo;
  const int kb_w = w >> 1;
  const int sub_w = (2 * w + (lo >> 3)) & 3;
  const int lanep = sub_w * 16 + hi * 4;  // + r
  const int jw = lo & 7;

  // ---- persistent register weights (pinned) ----
  const h8v* PAv = (const h8v*)PA;
  const h8v* PBv = (const h8v*)PB;
  h8v W0[4][6], W1[4][4];
#pragma unroll
  for (int q = 0; q < 4; ++q) {
#pragma unroll
    for (int ks = 0; ks < 6; ++ks) W0[q][ks] = PAv[((w * 4 + q) * 6 + ks) * 64 + l];
#pragma unroll
    for (int ks = 0; ks < 4; ++ks) W1[q][ks] = PBv[((w * 4 + q) * 8 + ks) * 64 + l];
  }
#pragma unroll
  for (int q = 0; q < 4; ++q) {
#pragma unroll
    for (int ks = 0; ks < 6; ++ks) asm volatile("" : "+v"(W0[q][ks]));
#pragma unroll
    for (int ks = 0; ks < 4; ++ks) asm volatile("" : "+v"(W1[q][ks]));
  }
  float bA[4], bB[4];
#pragma unroll
  for (int q = 0; q < 4; ++q) { bA[q] = b0[unit + 128 * q]; bB[q] = b1[unit + 128 * q]; }
  float c0[4] = {0.f, 0.f, 0.f, 0.f}, c1[4] = {0.f, 0.f, 0.f, 0.f};

  // ---- stage Whh1 fragments into LDS ----
  for (int i = tid; i < 8192; i += 512) {
    int l2 = i & 63, f = i >> 6;
    int ks4 = f & 3, wq = f >> 2;
    whh[i] = PBv[(wq * 8 + 4 + ks4) * 64 + l2];
  }
  // ---- zero h0t/h1t (both buffers), stage x(0) into xt[0] ----
  {
    unsigned int* z0 = (unsigned int*)h0t;
    unsigned int* z1 = (unsigned int*)h1t;
    for (int i = tid; i < 2048; i += 512) { z0[i] = 0u; z1[i] = 0u; }
    int row = tid >> 5, kk = (tid & 31) << 1;
    const float* xp = x + (((long)(g * 16 + row)) * T_STEPS + 0) * 64 + kk;
    float2 v = *(const float2*)xp;
    h2v pxv; pxv.x = (_Float16)v.x; pxv.y = (_Float16)v.y;
    *(h2v*)&xt[0][kk >> 5][(((kk >> 3) & 3) * 16) + row][kk & 7] = pxv;
  }
  __syncthreads();

  // Fused pipeline: iter j does A(j) [layer0 step j] and B(j-1) [layer1 step j-1].
  // Buffers: reads from [p=j&1], writes to [p^1]; one barrier per iter.
  for (int j = 0; j <= T_STEPS; ++j) {
    const int p = j & 1;

    // shared h0(j-1) fragments (A-operand for BOTH layers)
    h8v h00 = *(const h8v*)&h0t[p][0][l][0];
    h8v h01 = *(const h8v*)&h0t[p][1][l][0];
    h8v h02 = *(const h8v*)&h0t[p][2][l][0];
    h8v h03 = *(const h8v*)&h0t[p][3][l][0];

    if (j < T_STEPS) {
      // ---- A(j): layer 0 computes h0(j) ----
      h8v ax0 = *(const h8v*)&xt[p][0][l][0];
      h8v ax1 = *(const h8v*)&xt[p][1][l][0];
      f4v accA[4];
#pragma unroll
      for (int q = 0; q < 4; ++q) {
        f4v z = {bA[q], bA[q], bA[q], bA[q]};
        z = __builtin_amdgcn_mfma_f32_16x16x32_f16(ax0, W0[q][0], z, 0, 0, 0);
        z = __builtin_amdgcn_mfma_f32_16x16x32_f16(ax1, W0[q][1], z, 0, 0, 0);
        z = __builtin_amdgcn_mfma_f32_16x16x32_f16(h00, W0[q][2], z, 0, 0, 0);
        z = __builtin_amdgcn_mfma_f32_16x16x32_f16(h01, W0[q][3], z, 0, 0, 0);
        z = __builtin_amdgcn_mfma_f32_16x16x32_f16(h02, W0[q][4], z, 0, 0, 0);
        z = __builtin_amdgcn_mfma_f32_16x16x32_f16(h03, W0[q][5], z, 0, 0, 0);
        accA[q] = z;
      }
#pragma unroll
      for (int r = 0; r < 4; ++r) {
        float cn = sigf(accA[1][r]) * c0[r] + sigf(accA[0][r]) * tanh_(accA[2][r]);
        c0[r] = cn;
        float hv = sigf(accA[3][r]) * tanh_(cn);
        h0t[p ^ 1][kb_w][lanep + r][jw] = (_Float16)hv;
      }
      if (j + 1 < T_STEPS) {  // stage x(j+1) -> xt[p^1]
        int row = tid >> 5, kk = (tid & 31) << 1;
        const float* xp = x + (((long)(g * 16 + row)) * T_STEPS + (j + 1)) * 64 + kk;
        float2 v = *(const float2*)xp;
        h2v pxv; pxv.x = (_Float16)v.x; pxv.y = (_Float16)v.y;
        *(h2v*)&xt[p ^ 1][kk >> 5][(((kk >> 3) & 3) * 16) + row][kk & 7] = pxv;
      }
    }

    if (j >= 1) {
      // ---- B(j-1): layer 1 computes h1(j-1) ----
      h8v f10 = *(const h8v*)&h1t[p][0][l][0];
      h8v f11 = *(const h8v*)&h1t[p][1][l][0];
      h8v f12 = *(const h8v*)&h1t[p][2][l][0];
      h8v f13 = *(const h8v*)&h1t[p][3][l][0];
      f4v accB[4];
#pragma unroll
      for (int q = 0; q < 4; ++q) {
        const h8v* wb = &whh[((w * 4 + q) * 4) * 64 + l];
        h8v wh0 = wb[0];
        h8v wh1 = wb[64];
        h8v wh2 = wb[128];
        h8v wh3 = wb[192];
        f4v z = {bB[q], bB[q], bB[q], bB[q]};
        z = __builtin_amdgcn_mfma_f32_16x16x32_f16(h00, W1[q][0], z, 0, 0, 0);
        z = __builtin_amdgcn_mfma_f32_16x16x32_f16(h01, W1[q][1], z, 0, 0, 0);
        z = __builtin_amdgcn_mfma_f32_16x16x32_f16(h02, W1[q][2], z, 0, 0, 0);
        z = __builtin_amdgcn_mfma_f32_16x16x32_f16(h03, W1[q][3], z, 0, 0, 0);
        z = __builtin_amdgcn_mfma_f32_16x16x32_f16(f10, wh0, z, 0, 0, 0);
        z = __builtin_amdgcn_mfma_f32_16x16x32_f16(f11, wh1, z, 0, 0, 0);
        z = __builtin_amdgcn_mfma_f32_16x16x32_f16(f12, wh2, z, 0, 0, 0);
        z = __builtin_amdgcn_mfma_f32_16x16x32_f16(f13, wh3, z, 0, 0, 0);
        accB[q] = z;
      }
#pragma unroll
      for (int r = 0; r < 4; ++r) {
        float cn = sigf(accB[1][r]) * c1[r] + sigf(accB[0][r]) * tanh_(accB[2][r]);
        c1[r] = cn;
        float hv = sigf(accB[3][r]) * tanh_(cn);
        h1t[p ^ 1][kb_w][lanep + r][jw] = (_Float16)hv;
      }
    }
    __syncthreads();
  }

  // ---- output projection: y = h1(T-1) . Wout^T + bout ; h1(T-1) in h1t[1] ----
  if (tid < 16) {
    float acc = bout[0];
#pragma unroll 4
    for (int u = 0; u < 128; ++u) {
      float hval = (float)h1t[1][u >> 5][(((u >> 3) & 3) * 16) + tid][u & 7];
      acc = fmaf(hval, Wout[u], acc);
    }
    out[g * 16 + tid] = acc;
  }
}

}  // namespace

extern "C" void kernel_launch(void* const* d_in, const int* in_sizes, int n_in,
                              void* d_out, int out_size, void* d_ws, size_t ws_size,
                              hipStream_t stream) {
  const float* x    = (const float*)d_in[0];
  const float* Wih0 = (const float*)d_in[1];
  const float* Whh0 = (const float*)d_in[2];
  const float* b0   = (const float*)d_in[3];
  const float* Wih1 = (const float*)d_in[4];
  const float* Whh1 = (const float*)d_in[5];
  const float* b1   = (const float*)d_in[6];
  const float* Wout = (const float*)d_in[7];
  const float* bout = (const float*)d_in[8];
  float* out = (float*)d_out;

  char* ws = (char*)d_ws;
  _Float16* PA = (_Float16*)ws;             // 196608 B
  _Float16* PB = (_Float16*)(ws + 196608);  // 262144 B

  const int lds_bytes = 131072 + 8192 + 8192 + 4096;  // 151552
  hipFuncSetAttribute((const void*)lstm_block,
                      hipFuncAttributeMaxDynamicSharedMemorySize, lds_bytes);

  pack_w<<<dim3(896), dim3(256), 0, stream>>>(Wih0, Whh0, Wih1, Whh1, PA, PB);
  lstm_block<<<dim3(64), dim3(512), lds_bytes, stream>>>(
      x, PA, PB, b0, b1, Wout, bout, out);
}